// Round 7
// baseline (233.012 us; speedup 1.0000x reference)
//
#include <hip/hip_runtime.h>

// LearnedSegmentEncoder on MI355X — shared-slab ring-4 pipeline, counted vmcnt,
// raw barriers, 1KB-contiguous-per-instruction staging.
// B=8, C=128, P=65536, D=64, S=32.
// Identity: pooled = conv2_w @ mean_seg(relu(conv1_w@x+b1)) + b2, so only
// conv1 runs per-pixel (bf16 MFMA GEMM, M=B*P, N=64, K=128).
// Loop contains ZERO result-returning vmem and ZERO __syncthreads: the only
// vmem is our own global_load_lds stream (vmcnt arithmetic is exact), the only
// barriers are raw s_barrier (no compiler vmcnt(0) drain).

#define B_ 8
#define C_ 128
#define P_ 65536
#define D_ 64
#define S_ 32
#define PXT 256                  // pixels per block
#define ROWPAD 260               // floats per LDS channel-row (1040 B, 16B-aligned)

typedef short bf16x8 __attribute__((ext_vector_type(8)));
typedef float f32x4  __attribute__((ext_vector_type(4)));

__device__ __forceinline__ short f2bf(float f) {
  union { float f; unsigned u; } v; v.f = f;
  unsigned r = v.u + 0x7fffu + ((v.u >> 16) & 1u);   // RNE
  return (short)(r >> 16);
}

__global__ __launch_bounds__(256) void w1_to_bf16(const float* __restrict__ w1,
                                                  short* __restrict__ wbf) {
  int i = blockIdx.x * 256 + threadIdx.x;
  if (i < C_ * D_) wbf[i] = f2bf(w1[i]);
}

__device__ __forceinline__ void gload16(const float* g, const float* l) {
  __builtin_amdgcn_global_load_lds(
      (const __attribute__((address_space(1))) float*)g,
      (__attribute__((address_space(3))) float*)l, 16, 0, 0);
}

// Grid (P/PXT, B) = (256, 8) = 2048 blocks; 256 thr = 4 waves.
// Chunk = 16 channel-rows x 256 px f32; ring of 4 chunks; consume in pairs
// (32 ch = one MFMA K-step). Wave w stages rows 4w..4w+3 (1 instr = 1 row,
// 1 KB contiguous) and consumes pixel sub-range [64w, 64w+64).
__global__ __launch_bounds__(256, 2) void proj_mfma(
    const int* __restrict__ labels, const float* __restrict__ feat,
    const short* __restrict__ wbf, const float* __restrict__ b1,
    float* __restrict__ gsum, int* __restrict__ gcnt)
{
  __shared__ __align__(16) float ring[4][16 * ROWPAD];   // 65 KB
  __shared__ float s_acc[S_][68];                        // 8.5 KB
  __shared__ int   s_cnt[S_];

  const int tid  = threadIdx.x;
  const int wave = tid >> 6, l = tid & 63, m = l & 15, g = l >> 4;
  const int b    = blockIdx.y;
  const int px0  = blockIdx.x * PXT;

  for (int i = tid; i < S_ * 68; i += 256) ((float*)s_acc)[i] = 0.f;
  if (tid < S_) s_cnt[tid] = 0;
  // (ordering vs epilogue scatter is provided by the loop's s_barriers)

  // ---- one-time register prologue: W1^T fragments + bias ----
  // bfr[nt][u] = wbf[(nt*16+m)*C + u*32 + g*8 .. +7]  (16 B contiguous)
  bf16x8 bfr[4][4];
  #pragma unroll
  for (int nt = 0; nt < 4; ++nt)
    #pragma unroll
    for (int u = 0; u < 4; ++u)
      bfr[nt][u] = *(const bf16x8*)&wbf[(nt * 16 + m) * C_ + u * 32 + g * 8];
  float b1v[4];
  #pragma unroll
  for (int nt = 0; nt < 4; ++nt) b1v[nt] = b1[nt * 16 + m];
  // compiler inserts vmcnt waits for the uses above -> vmem count is 0 here

  const float* xb = feat + (size_t)b * C_ * P_ + px0;

  // stage chunk c: channel-rows c*16 + (4*wave + i), 1 KB contiguous each
#define STAGE(c_) do {                                                        \
    _Pragma("unroll") for (int i = 0; i < 4; ++i)                             \
      gload16(xb + (size_t)((c_) * 16 + wave * 4 + i) * P_ + l * 4,           \
              &ring[(c_) & 3][(wave * 4 + i) * ROWPAD]);                      \
  } while (0)

#define WAITV(n_) do {                                                        \
    asm volatile("s_waitcnt vmcnt(" #n_ ")" ::: "memory");                    \
    __builtin_amdgcn_sched_barrier(0);                                        \
  } while (0)

  // consume pair u (channels u*32..u*32+31 = ring slots (2u)&3,(2u+1)&3)
#define PAIR(u_) do {                                                         \
    _Pragma("unroll") for (int v = 0; v < 4; ++v) {                           \
      const int px = wave * 64 + v * 16 + m;                                  \
      const float* sl = &ring[(2 * (u_) + (g >> 1)) & 3]                      \
                             [((g & 1) * 8) * ROWPAD + px];                   \
      bf16x8 af;                                                              \
      _Pragma("unroll") for (int j = 0; j < 8; ++j)                           \
        af[j] = f2bf(sl[j * ROWPAD]);                                         \
      _Pragma("unroll") for (int nt = 0; nt < 4; ++nt)                        \
        acc[v][nt] = __builtin_amdgcn_mfma_f32_16x16x32_bf16(                 \
            af, bfr[nt][u_], acc[v][nt], 0, 0, 0);                            \
    }                                                                         \
  } while (0)

  STAGE(0); STAGE(1); STAGE(2); STAGE(3);          // 16 outstanding

  f32x4 acc[4][4];
  #pragma unroll
  for (int v = 0; v < 4; ++v)
    #pragma unroll
    for (int nt = 0; nt < 4; ++nt) acc[v][nt] = (f32x4){0.f, 0.f, 0.f, 0.f};

  // u=0
  WAITV(8);                                        // chunks 0,1 (ours) landed
  __builtin_amdgcn_s_barrier();                    // everyone's rows present
  PAIR(0);
  __builtin_amdgcn_sched_barrier(0);
  __builtin_amdgcn_s_barrier();                    // all reads of slots 0,1 done
  STAGE(4); STAGE(5);                              // refill slots 0,1 -> 16 out
  // u=1
  WAITV(8);                                        // chunks 2,3 landed
  __builtin_amdgcn_s_barrier();
  PAIR(1);
  __builtin_amdgcn_sched_barrier(0);
  __builtin_amdgcn_s_barrier();
  STAGE(6); STAGE(7);                              // refill slots 2,3 -> 16 out
  // u=2
  WAITV(8);                                        // chunks 4,5 landed
  __builtin_amdgcn_s_barrier();
  PAIR(2);
  __builtin_amdgcn_sched_barrier(0);
  // u=3 (slots not reused: no second barrier/stage needed)
  WAITV(0);                                        // chunks 6,7 landed
  __builtin_amdgcn_s_barrier();
  PAIR(3);
  __builtin_amdgcn_sched_barrier(0);

#undef STAGE
#undef WAITV
#undef PAIR

  // ---- epilogue: relu + bias, label scatter into LDS, global flush ----
  const int* lb = labels + (size_t)b * P_ + px0 + wave * 64;
  #pragma unroll
  for (int v = 0; v < 4; ++v) {
    const int4 lv = *(const int4*)&lb[v * 16 + g * 4];
    #pragma unroll
    for (int nt = 0; nt < 4; ++nt) {
      #pragma unroll
      for (int r = 0; r < 4; ++r) {
        const int lab = ((r & 2) ? ((r & 1) ? lv.w : lv.z)
                                 : ((r & 1) ? lv.y : lv.x)) & (S_ - 1);
        atomicAdd(&s_acc[lab][nt * 16 + m],
                  fmaxf(acc[v][nt][r] + b1v[nt], 0.f));
      }
    }
    if (m < 4) {
      const int lab = ((m & 2) ? ((m & 1) ? lv.w : lv.z)
                               : ((m & 1) ? lv.y : lv.x)) & (S_ - 1);
      atomicAdd(&s_cnt[lab], 1);
    }
  }

  __syncthreads();
  for (int i = tid; i < S_ * D_; i += 256)
    atomicAdd(&gsum[(size_t)b * S_ * D_ + i], s_acc[i >> 6][i & 63]);
  if (tid < S_) atomicAdd(&gcnt[b * S_ + tid], s_cnt[tid]);
}

// Grid (S, B), 64 lanes: all (b,s) blocks independent; ballot-based rank.
__global__ __launch_bounds__(64) void seg_finalize2(
    const float* __restrict__ gsum, const int* __restrict__ gcnt,
    const float* __restrict__ w2, const float* __restrict__ b2,
    const float* __restrict__ emb, const float* __restrict__ wo,
    const float* __restrict__ bo, float* __restrict__ out)
{
  const int s = blockIdx.x, b = blockIdx.y, o = threadIdx.x;
  const int co = (o < S_) ? gcnt[b * S_ + o] : 0;
  const unsigned long long mask = __ballot(co > 0);
  const int cnt = gcnt[b * S_ + s];
  if (cnt <= 0) return;                               // uniform exit
  const int rank = __popcll(mask & ((1ull << s) - 1ull));

  __shared__ float s_mean[D_], s_pool[D_];
  s_mean[o] = gsum[((size_t)b * S_ + s) * D_ + o] * (1.f / (float)cnt);
  __syncthreads();
  float pooled = b2[o];
  #pragma unroll
  for (int d = 0; d < D_; ++d) pooled += w2[o * D_ + d] * s_mean[d];
  s_pool[o] = pooled;
  __syncthreads();
  float r = bo[o];
  #pragma unroll
  for (int e = 0; e < D_; ++e) r += wo[o * 2 * D_ + e] * s_pool[e];
  #pragma unroll
  for (int e = 0; e < D_; ++e) r += wo[o * 2 * D_ + D_ + e] * emb[s * D_ + e];
  out[((size_t)b * S_ + rank) * D_ + o] = r;
}

extern "C" void kernel_launch(void* const* d_in, const int* in_sizes, int n_in,
                              void* d_out, int out_size, void* d_ws, size_t ws_size,
                              hipStream_t stream) {
  const int*   labels = (const int*)  d_in[0];
  const float* feat   = (const float*)d_in[1];
  const float* w1     = (const float*)d_in[2];
  const float* b1     = (const float*)d_in[3];
  const float* w2     = (const float*)d_in[4];
  const float* b2     = (const float*)d_in[5];
  const float* emb    = (const float*)d_in[6];
  const float* wo     = (const float*)d_in[7];
  const float* bo     = (const float*)d_in[8];
  float* out = (float*)d_out;

  // ws layout: gsum | gcnt | wbf
  char* w = (char*)d_ws;
  float* gsum = (float*)w;   w += (size_t)B_ * S_ * D_ * 4;
  int*   gcnt = (int*)w;     w += (size_t)B_ * S_ * 4;
  short* wbf  = (short*)w;

  hipMemsetAsync(d_ws, 0, (size_t)B_ * S_ * D_ * 4 + (size_t)B_ * S_ * 4, stream);
  hipMemsetAsync(d_out, 0, (size_t)out_size * sizeof(float), stream);

  w1_to_bf16<<<(C_ * D_ + 255) / 256, 256, 0, stream>>>(w1, wbf);

  dim3 grid(P_ / PXT, B_);
  proj_mfma<<<grid, 256, 0, stream>>>(labels, feat, wbf, b1, gsum, gcnt);
  seg_finalize2<<<dim3(S_, B_), 64, 0, stream>>>(gsum, gcnt, w2, b2, emb, wo, bo, out);
}

// Round 8
// 223.886 us; speedup vs baseline: 1.0408x; 1.0408x over previous
//
#include <hip/hip_runtime.h>

// LearnedSegmentEncoder on MI355X — long-run (4KB) staging experiment.
// B=8, C=128, P=65536, D=64, S=32.
// Identity: pooled = conv2_w @ mean_seg(relu(conv1_w@x+b1)) + b2, so only
// conv1 runs per-pixel (bf16 MFMA GEMM). Hypothesis under test: the ~1.2 TB/s
// wall of R2-R7 is caused by short (<=1KB) runs at 256KB stride; this kernel
// reads 4KB contiguous per channel-row visit (1024 px/block), 32x32x16 MFMA,
// ring-4 LDS (128KB), counted vmcnt, raw barriers, no vmem results in loop.

#define B_ 8
#define C_ 128
#define P_ 65536
#define D_ 64
#define S_ 32
#define PXB 1024                // pixels per block
#define RP  1024                // ring row pitch (floats)
#define WP  136                 // wlds row pitch (bf16), keeps 16B align

typedef short bf16x8 __attribute__((ext_vector_type(8)));
typedef float f32x16 __attribute__((ext_vector_type(16)));

__device__ __forceinline__ short f2bf(float f) {
  union { float f; unsigned u; } v; v.f = f;
  unsigned r = v.u + 0x7fffu + ((v.u >> 16) & 1u);   // RNE
  return (short)(r >> 16);
}

__global__ __launch_bounds__(256) void w1_to_bf16(const float* __restrict__ w1,
                                                  short* __restrict__ wbf) {
  int i = blockIdx.x * 256 + threadIdx.x;
  if (i < C_ * D_) wbf[i] = f2bf(w1[i]);
}

__device__ __forceinline__ void gload16(const float* g, const float* l) {
  __builtin_amdgcn_global_load_lds(
      (const __attribute__((address_space(1))) float*)g,
      (__attribute__((address_space(3))) float*)l, 16, 0, 0);
}

// Grid 512 blocks x 512 thr (8 waves). Block owns 1024 px x 128 ch.
// Chunk = 8 ch x 1024 px f32 (32 KB): wave w stages channel-row w as
// 4 back-to-back 1KB gload16 (a 4KB contiguous run). Ring of 4 chunks
// = 2 K-steps of mfma_32x32x16 (K=16ch = 2 chunks). XCD swizzle maps
// batch b -> XCD b so 32 CUs co-stream adjacent windows of the same rows.
__global__ __launch_bounds__(512, 2) void proj_mfma(
    const int* __restrict__ labels, const float* __restrict__ feat,
    const short* __restrict__ wbf, const float* __restrict__ b1,
    float* __restrict__ gsum, int* __restrict__ gcnt)
{
  __shared__ __align__(16) float ring[4][8 * RP];      // 128 KB
  __shared__ __align__(16) short wlds[D_ * WP];        // 17 KB
  __shared__ float s_acc[S_][68];                      // 8.5 KB
  __shared__ int   s_cnt[S_];

  const int tid = threadIdx.x;
  const int w = tid >> 6, l = tid & 63, n = l & 31, h = l >> 5;
  const int bid = blockIdx.x;
  const int wk  = (bid & 7) * 64 + (bid >> 3);         // XCD-contiguous work id
  const int b   = wk >> 6;                             // batch == XCD
  const int px0 = (wk & 63) * PXB;

  for (int i = tid; i < S_ * 68; i += 512) ((float*)s_acc)[i] = 0.f;
  if (tid < S_) s_cnt[tid] = 0;
  {                                                    // W1^T -> LDS (pitch WP)
    const int d = tid >> 3, c0 = (tid & 7) * 16;
    *(bf16x8*)&wlds[d * WP + c0]     = *(const bf16x8*)&wbf[d * C_ + c0];
    *(bf16x8*)&wlds[d * WP + c0 + 8] = *(const bf16x8*)&wbf[d * C_ + c0 + 8];
  }

  const float* xb = feat + (size_t)b * C_ * P_ + px0;

  // chunk ci (0..15): channels ci*8 .. ci*8+7; wave w stages row w.
#define STAGE(ci) do {                                                        \
    _Pragma("unroll") for (int i = 0; i < 4; ++i)                             \
      gload16(xb + (size_t)((ci) * 8 + w) * P_ + i * 256 + l * 4,             \
              &ring[(ci) & 3][w * RP + i * 256]);                             \
  } while (0)

#define WAITV(n_) do {                                                        \
    asm volatile("s_waitcnt vmcnt(" #n_ ")" ::: "memory");                    \
    __builtin_amdgcn_sched_barrier(0);                                        \
  } while (0)

  STAGE(0); STAGE(1); STAGE(2); STAGE(3);              // 16 outstanding/wave
  asm volatile("s_waitcnt lgkmcnt(0)" ::: "memory");   // LDS init drained
  __builtin_amdgcn_sched_barrier(0);

  f32x16 acc[4][2];
  #pragma unroll
  for (int v = 0; v < 4; ++v)
    #pragma unroll
    for (int nt = 0; nt < 2; ++nt)
      #pragma unroll
      for (int e = 0; e < 16; ++e) acc[v][nt][e] = 0.f;

  // K-step ks consumes chunks 2ks (h=0) and 2ks+1 (h=1); A lane (n,h):
  // A[px = tile*32+n][k = h*8+j]; B lane: B[k = h*8+j][d = nt*32+n].
  #pragma unroll
  for (int ks = 0; ks < 8; ++ks) {
    if (ks < 7) { WAITV(8); } else { WAITV(0); }
    __builtin_amdgcn_s_barrier();
    __builtin_amdgcn_sched_barrier(0);

    const bf16x8 bw0 = *(const bf16x8*)&wlds[n * WP + ks * 16 + h * 8];
    const bf16x8 bw1 = *(const bf16x8*)&wlds[(32 + n) * WP + ks * 16 + h * 8];
    const float* rs = &ring[(2 * ks + h) & 3][0];
    #pragma unroll
    for (int v = 0; v < 4; ++v) {
      bf16x8 af;
      #pragma unroll
      for (int j = 0; j < 8; ++j)
        af[j] = f2bf(rs[j * RP + (w * 4 + v) * 32 + n]);
      acc[v][0] = __builtin_amdgcn_mfma_f32_32x32x16_bf16(af, bw0, acc[v][0], 0, 0, 0);
      acc[v][1] = __builtin_amdgcn_mfma_f32_32x32x16_bf16(af, bw1, acc[v][1], 0, 0, 0);
    }
    __builtin_amdgcn_sched_barrier(0);
    __builtin_amdgcn_s_barrier();                      // reads of slots done
    __builtin_amdgcn_sched_barrier(0);
    if (ks < 6) { STAGE(2 * ks + 4); STAGE(2 * ks + 5); }
  }
#undef STAGE
#undef WAITV

  // ---- epilogue: relu+bias, label scatter (C/D: col=n=d, row=(r&3)+8*(r>>2)+4h) ----
  const float b1v0 = b1[n];
  const float b1v1 = b1[32 + n];
  const int* lb = labels + (size_t)b * P_ + px0;
  #pragma unroll
  for (int v = 0; v < 4; ++v) {
    const int tb = (w * 4 + v) * 32;
    #pragma unroll
    for (int q = 0; q < 4; ++q) {
      const int4 lv = *(const int4*)&lb[tb + q * 8 + h * 4];
      #pragma unroll
      for (int r2 = 0; r2 < 4; ++r2) {
        const int lab = ((r2 & 2) ? ((r2 & 1) ? lv.w : lv.z)
                                  : ((r2 & 1) ? lv.y : lv.x)) & (S_ - 1);
        const int rg = q * 4 + r2;
        atomicAdd(&s_acc[lab][n],      fmaxf(acc[v][0][rg] + b1v0, 0.f));
        atomicAdd(&s_acc[lab][32 + n], fmaxf(acc[v][1][rg] + b1v1, 0.f));
        if (n == 0) atomicAdd(&s_cnt[lab], 1);         // one inc per pixel (per h)
      }
    }
  }

  __syncthreads();
  for (int i = tid; i < S_ * D_; i += 512)
    atomicAdd(&gsum[(size_t)b * S_ * D_ + i], s_acc[i >> 6][i & 63]);
  if (tid < S_) atomicAdd(&gcnt[b * S_ + tid], s_cnt[tid]);
}

// Grid (S, B), 64 lanes: all (b,s) blocks independent; ballot-based rank.
__global__ __launch_bounds__(64) void seg_finalize2(
    const float* __restrict__ gsum, const int* __restrict__ gcnt,
    const float* __restrict__ w2, const float* __restrict__ b2,
    const float* __restrict__ emb, const float* __restrict__ wo,
    const float* __restrict__ bo, float* __restrict__ out)
{
  const int s = blockIdx.x, b = blockIdx.y, o = threadIdx.x;
  const int co = (o < S_) ? gcnt[b * S_ + o] : 0;
  const unsigned long long mask = __ballot(co > 0);
  const int cnt = gcnt[b * S_ + s];
  if (cnt <= 0) return;                               // uniform exit
  const int rank = __popcll(mask & ((1ull << s) - 1ull));

  __shared__ float s_mean[D_], s_pool[D_];
  s_mean[o] = gsum[((size_t)b * S_ + s) * D_ + o] * (1.f / (float)cnt);
  __syncthreads();
  float pooled = b2[o];
  #pragma unroll
  for (int d = 0; d < D_; ++d) pooled += w2[o * D_ + d] * s_mean[d];
  s_pool[o] = pooled;
  __syncthreads();
  float r = bo[o];
  #pragma unroll
  for (int e = 0; e < D_; ++e) r += wo[o * 2 * D_ + e] * s_pool[e];
  #pragma unroll
  for (int e = 0; e < D_; ++e) r += wo[o * 2 * D_ + D_ + e] * emb[s * D_ + e];
  out[((size_t)b * S_ + rank) * D_ + o] = r;
}

extern "C" void kernel_launch(void* const* d_in, const int* in_sizes, int n_in,
                              void* d_out, int out_size, void* d_ws, size_t ws_size,
                              hipStream_t stream) {
  const int*   labels = (const int*)  d_in[0];
  const float* feat   = (const float*)d_in[1];
  const float* w1     = (const float*)d_in[2];
  const float* b1     = (const float*)d_in[3];
  const float* w2     = (const float*)d_in[4];
  const float* b2     = (const float*)d_in[5];
  const float* emb    = (const float*)d_in[6];
  const float* wo     = (const float*)d_in[7];
  const float* bo     = (const float*)d_in[8];
  float* out = (float*)d_out;

  // ws layout: gsum | gcnt | wbf
  char* w = (char*)d_ws;
  float* gsum = (float*)w;   w += (size_t)B_ * S_ * D_ * 4;
  int*   gcnt = (int*)w;     w += (size_t)B_ * S_ * 4;
  short* wbf  = (short*)w;

  hipMemsetAsync(d_ws, 0, (size_t)B_ * S_ * D_ * 4 + (size_t)B_ * S_ * 4, stream);
  hipMemsetAsync(d_out, 0, (size_t)out_size * sizeof(float), stream);

  w1_to_bf16<<<(C_ * D_ + 255) / 256, 256, 0, stream>>>(w1, wbf);

  proj_mfma<<<(P_ / PXB) * B_, 512, 0, stream>>>(labels, feat, wbf, b1, gsum, gcnt);
  seg_finalize2<<<dim3(S_, B_), 64, 0, stream>>>(gsum, gcnt, w2, b2, emb, wo, bo, out);
}